// Round 2
// baseline (237.639 us; speedup 1.0000x reference)
//
#include <hip/hip_runtime.h>
#include <math.h>

#define BB 2
#define NN 1024
#define F_IN 128
#define HH 4
#define HID 32
#define NC 16          // j-chunks per row
#define CJ (NN/NC)     // 64 j's per chunk (= one u64 bitmask word)

// ---- workspace layout (bytes) ----
// x    @ 0        : B*H*N*HID f32   = 1048576
// d6   @ 1048576  : B*H*N f32       = 32768     (0.6 * Wa.x per node)
// bits @ 1081344  : B*N*N/8 bytes   = 262144    (u64 per 64 adj entries)
// accg @ 1343488  : B*H*N*HID f32   = 1048576   (atomic partial numerators)
// lg   @ 2392064  : B*H*N f32       = 32768     (atomic partial denominators)
#define WS_X    0
#define WS_D6   1048576
#define WS_BITS 1081344
#define WS_ACC  1343488
#define WS_LG   2392064

// ---------------- Kernel 1: projection x = feat@W (B,H,N,HID) + d6 = 0.6*(x.wa)
__global__ __launch_bounds__(128) void gat_proj_kernel(const float* __restrict__ feat,
                                                       const float* __restrict__ W,
                                                       const float* __restrict__ Wa,
                                                       float* __restrict__ xout,
                                                       float* __restrict__ d6) {
    const int RPB = 8; // node rows per block
    int blk = blockIdx.x;             // 0 .. B*N/RPB-1
    int b  = blk / (NN / RPB);
    int n0 = (blk % (NN / RPB)) * RPB;
    int t  = threadIdx.x;             // 0..127 -> output column c = h*HID+k

    __shared__ float fs[RPB][F_IN];
    for (int e = t; e < RPB * F_IN; e += 128) {
        int r = e >> 7;
        int f = e & 127;
        fs[r][f] = feat[((size_t)(b * NN + n0 + r)) * F_IN + f];
    }
    __syncthreads();

    float acc[RPB];
#pragma unroll
    for (int r = 0; r < RPB; ++r) acc[r] = 0.f;

    for (int f = 0; f < F_IN; ++f) {
        float w = W[f * (HH * HID) + t];
#pragma unroll
        for (int r = 0; r < RPB; ++r) acc[r] = fmaf(fs[r][f], w, acc[r]);
    }

    int h = t >> 5, k = t & 31;
    float w_t = Wa[t];   // Wa is H*HID = 128 floats flat; t = h*32+k
#pragma unroll
    for (int r = 0; r < RPB; ++r) {
        xout[(((size_t)(b * HH + h)) * NN + (n0 + r)) * HID + k] = acc[r];
        // reduce acc[r]*wa over the 32 k-lanes of this h-group
        float prod = acc[r] * w_t;
#pragma unroll
        for (int off = 16; off >= 1; off >>= 1)
            prod += __shfl_xor(prod, off, 32);
        if (k == 0)
            d6[((size_t)(b * HH + h)) * NN + (n0 + r)] = 0.6f * prod;
    }
}

// ---------------- Kernel 2: pack adjacency to bitmask + zero the atomic buffers
__global__ __launch_bounds__(256) void gat_pack_kernel(const int* __restrict__ adj,
                                                       unsigned long long* __restrict__ bits,
                                                       float* __restrict__ zero_region) {
    int gid = blockIdx.x * 256 + threadIdx.x;    // 0 .. B*N*N-1
    int v = adj[gid];
    unsigned long long m = __ballot(v > 0);
    if ((threadIdx.x & 63) == 0) bits[gid >> 6] = m;
    // fold in zeroing of accg+lg (270336 floats) to save a launch node
    if (gid < (1048576 + 32768) / 4) zero_region[gid] = 0.f;
}

// ---------------- Kernel 3: fused scores + fixed-m softmax partials + aggregate
// One wave per (row-group of 64 rows, j-chunk of 64). lane = query row.
__global__ __launch_bounds__(64) void gat_attn_kernel(const float* __restrict__ x,
                                                      const float* __restrict__ d6,
                                                      const unsigned long long* __restrict__ bits,
                                                      const float* __restrict__ Wa,
                                                      float* __restrict__ accg,
                                                      float* __restrict__ lg) {
    int blk = blockIdx.x;            // 0 .. 2047
    int c   = blk & (NC - 1);        // j-chunk
    int rg  = blk >> 4;              // 0..127 row group
    int bh  = rg >> 4;               // (b*H+h), 16 row-groups per bh
    int i0  = (rg & 15) * 64;
    int h   = bh & (HH - 1);
    int b   = bh >> 2;
    int l   = threadIdx.x;           // lane
    int i   = i0 + l;                // this lane's query row

    const float* xbh = x  + (size_t)bh * NN * HID;
    const float* dbh = d6 + (size_t)bh * NN;

    // per-lane row data in registers
    float xi[HID];
#pragma unroll
    for (int k = 0; k < HID; ++k) xi[k] = xbh[(size_t)i * HID + k];
    float wa4[HID];
#pragma unroll
    for (int k = 0; k < HID; ++k) wa4[k] = 0.4f * Wa[h * HID + k];
    float ci = dbh[i];

    unsigned long long w64 = bits[((size_t)b * NN + i) * NC + c];
    unsigned int wlo = (unsigned int)w64;
    unsigned int whi = (unsigned int)(w64 >> 32);

    const float* xj_base = xbh + (size_t)(c * CJ) * HID;   // uniform across wave
    const float* dj_base = dbh + c * CJ;

    float acc[HID];
#pragma unroll
    for (int k = 0; k < HID; ++k) acc[k] = 0.f;
    float lsum = 0.f;

#pragma unroll
    for (int half = 0; half < 2; ++half) {
        unsigned int w = half ? whi : wlo;
#pragma unroll 4
        for (int jj = 0; jj < 32; ++jj) {
            int j = half * 32 + jj;
            // wave-uniform loads -> SMEM (s_load) path
            float xj[HID];
#pragma unroll
            for (int k = 0; k < HID; ++k) xj[k] = xj_base[j * HID + k];
            float dj = dj_base[j];

            // e = 0.6*(d_i+d_j) + sum_k 0.4*wa_k*|x_i+x_j|   (== wa . lrelu(x_i+x_j))
            float s4a = 0.f, s4b = 0.f, s4c = 0.f, s4d = 0.f;
#pragma unroll
            for (int k = 0; k < HID; k += 4) {
                float v0 = xi[k]     + xj[k];     s4a = fmaf(wa4[k],     fabsf(v0), s4a);
                float v1 = xi[k + 1] + xj[k + 1]; s4b = fmaf(wa4[k + 1], fabsf(v1), s4b);
                float v2 = xi[k + 2] + xj[k + 2]; s4c = fmaf(wa4[k + 2], fabsf(v2), s4c);
                float v3 = xi[k + 3] + xj[k + 3]; s4d = fmaf(wa4[k + 3], fabsf(v3), s4d);
            }
            float e = (ci + dj) + ((s4a + s4b) + (s4c + s4d));
            float p = __expf(e);                 // fixed m=0: softmax shift-invariant
            p = ((w >> jj) & 1u) ? p : 0.f;      // adjacency mask
            lsum += p;
#pragma unroll
            for (int k = 0; k < HID; ++k) acc[k] = fmaf(p, xj[k], acc[k]);
        }
    }

    // combine chunk partials (fixed m -> directly addable)
    float* arow = accg + ((size_t)bh * NN + i) * HID;
#pragma unroll
    for (int k = 0; k < HID; ++k) atomicAdd(&arow[k], acc[k]);
    atomicAdd(&lg[(size_t)bh * NN + i], lsum);
}

// ---------------- Kernel 4: out = acc / l  (with head-concat transpose)
__global__ __launch_bounds__(256) void gat_final_kernel(const float* __restrict__ accg,
                                                        const float* __restrict__ lg,
                                                        float* __restrict__ out) {
    int t = blockIdx.x * 256 + threadIdx.x;      // 0 .. B*H*N*HID-1
    int k  = t & 31;
    int n  = (t >> 5) & (NN - 1);
    int bh = t >> 15;
    int h  = bh & (HH - 1);
    int b  = bh >> 2;
    float inv = lg[(size_t)bh * NN + n];
    out[((size_t)(b * NN + n)) * (HH * HID) + h * HID + k] = accg[t] / inv;
}

extern "C" void kernel_launch(void* const* d_in, const int* in_sizes, int n_in,
                              void* d_out, int out_size, void* d_ws, size_t ws_size,
                              hipStream_t stream) {
    const float* node_feat = (const float*)d_in[0];
    const int*   adj_mtx   = (const int*)d_in[1];
    const float* W         = (const float*)d_in[2];
    const float* Wa        = (const float*)d_in[3];
    float* out = (float*)d_out;

    char* ws = (char*)d_ws;
    float*              x_ws  = (float*)(ws + WS_X);
    float*              d6_ws = (float*)(ws + WS_D6);
    unsigned long long* bits  = (unsigned long long*)(ws + WS_BITS);
    float*              accg  = (float*)(ws + WS_ACC);
    float*              lg    = (float*)(ws + WS_LG);

    // projection + d6
    hipLaunchKernelGGL(gat_proj_kernel, dim3(BB * NN / 8), dim3(128), 0, stream,
                       node_feat, W, Wa, x_ws, d6_ws);
    // adjacency bit-pack + zero atomic buffers (accg,lg are contiguous)
    hipLaunchKernelGGL(gat_pack_kernel, dim3(BB * NN * NN / 256), dim3(256), 0, stream,
                       adj_mtx, bits, accg);
    // fused attention partials
    hipLaunchKernelGGL(gat_attn_kernel, dim3((BB * HH * NN / 64) * NC), dim3(64), 0, stream,
                       x_ws, d6_ws, bits, Wa, accg, lg);
    // finalize
    hipLaunchKernelGGL(gat_final_kernel, dim3(BB * HH * NN * HID / 256), dim3(256), 0, stream,
                       accg, lg, out);
}

// Round 3
// 55.594 us; speedup vs baseline: 4.2745x; 4.2745x over previous
//
#include <hip/hip_runtime.h>
#include <math.h>

#define BB 2
#define NN 1024
#define F_IN 128
#define HH 4
#define HID 32
#define TJ 64
#define NT (NN/TJ)     // 16 j-tiles, one u64 bitmask word each

// ---- workspace layout (bytes) ----
#define WS_X    0              // B*H*N*HID f32 = 1048576
#define WS_D6   1048576        // B*H*N f32     = 32768
#define WS_BITS 1081344        // B*N*N/8       = 262144

// ---------------- Kernel 1: projection x = feat@W (B,H,N,HID) + d6 = 0.6*(x.wa)
__global__ __launch_bounds__(128) void gat_proj_kernel(const float* __restrict__ feat,
                                                       const float* __restrict__ W,
                                                       const float* __restrict__ Wa,
                                                       float* __restrict__ xout,
                                                       float* __restrict__ d6) {
    const int RPB = 8;
    int blk = blockIdx.x;
    int b  = blk / (NN / RPB);
    int n0 = (blk % (NN / RPB)) * RPB;
    int t  = threadIdx.x;

    __shared__ float fs[RPB][F_IN];
    for (int e = t; e < RPB * F_IN; e += 128) {
        int r = e >> 7;
        int f = e & 127;
        fs[r][f] = feat[((size_t)(b * NN + n0 + r)) * F_IN + f];
    }
    __syncthreads();

    float acc[RPB];
#pragma unroll
    for (int r = 0; r < RPB; ++r) acc[r] = 0.f;

    for (int f = 0; f < F_IN; ++f) {
        float w = W[f * (HH * HID) + t];
#pragma unroll
        for (int r = 0; r < RPB; ++r) acc[r] = fmaf(fs[r][f], w, acc[r]);
    }

    int h = t >> 5, k = t & 31;
    float w_t = Wa[t];
#pragma unroll
    for (int r = 0; r < RPB; ++r) {
        xout[(((size_t)(b * HH + h)) * NN + (n0 + r)) * HID + k] = acc[r];
        float prod = acc[r] * w_t;
#pragma unroll
        for (int off = 16; off >= 1; off >>= 1)
            prod += __shfl_xor(prod, off, 32);
        if (k == 0)
            d6[((size_t)(b * HH + h)) * NN + (n0 + r)] = 0.6f * prod;
    }
}

// ---------------- Kernel 2: pack adjacency to bitmask
__global__ __launch_bounds__(256) void gat_pack_kernel(const int* __restrict__ adj,
                                                       unsigned long long* __restrict__ bits) {
    int gid = blockIdx.x * 256 + threadIdx.x;
    unsigned long long m = __ballot(adj[gid] > 0);
    if ((threadIdx.x & 63) == 0) bits[gid >> 6] = m;
}

// ---------------- Kernel 3: fused attention. Block = 512 thr (8 waves), 16 query rows.
// Wave w owns rows iA=ibase+2w, iB=iA+1 (uniform); lane = j within the LDS tile.
// Fixed-m softmax (m=0): per-lane p, per-lane partial acc[k]; one transpose-reduce at end.
__global__ __launch_bounds__(512, 2) void gat_attn_kernel(const float* __restrict__ x,
                                                          const float* __restrict__ d6,
                                                          const unsigned long long* __restrict__ bits,
                                                          const float* __restrict__ Wa,
                                                          float* __restrict__ out) {
    int blk = blockIdx.x;                 // 0..511
    int tid = threadIdx.x;
    int w   = __builtin_amdgcn_readfirstlane(tid >> 6);   // wave id, force SGPR-uniform
    int l   = tid & 63;
    int bh    = blk >> 6;                 // 64 blocks per (b,h)
    int ibase = (blk & 63) << 4;          // 16 rows per block
    int h = bh & (HH - 1);
    int b = bh >> 2;
    int iA = ibase + 2 * w;
    int iB = iA + 1;

    const float* xbh = x  + (size_t)bh * NN * HID;
    const float* dbh = d6 + (size_t)bh * NN;
    const unsigned long long* brA = bits + ((size_t)b * NN + iA) * NT;
    const unsigned long long* brB = bits + ((size_t)b * NN + iB) * NT;

    // wave-uniform row data (uniform addresses -> scalar loads)
    float xiA[HID], xiB[HID], wa4[HID];
#pragma unroll
    for (int k = 0; k < HID; ++k) {
        xiA[k] = xbh[(size_t)iA * HID + k];
        xiB[k] = xbh[(size_t)iB * HID + k];
        wa4[k] = 0.4f * Wa[h * HID + k];
    }
    float ciA = dbh[iA], ciB = dbh[iB];

    __shared__ float xs[2][TJ][36];       // pad 36 -> conflict-free ds_read_b128
    __shared__ float xd[2][TJ];
    __shared__ float scr[4][HID][65];     // epilogue transpose (waves share in 2 rounds)

    float accA[HID], accB[HID];
#pragma unroll
    for (int k = 0; k < HID; ++k) { accA[k] = 0.f; accB[k] = 0.f; }
    float lsA = 0.f, lsB = 0.f;

    // staging geometry: 512 threads x 1 float4 = 64 rows x 32 cols
    int jj = tid >> 3, k4 = (tid & 7) << 2;

    // prefetch tile 0
    float4 pre = *(const float4*)(xbh + jj * HID + k4);
    float pred = (tid < TJ) ? dbh[tid] : 0.f;

    for (int t = 0; t < NT; ++t) {
        int bc = t & 1;
        *(float4*)&xs[bc][jj][k4] = pre;
        if (tid < TJ) xd[bc][tid] = pred;
        __syncthreads();
        if (t + 1 < NT) {   // issue next-tile loads early; regs unused until next iter's write
            const float* src = xbh + (size_t)(t + 1) * TJ * HID;
            pre = *(const float4*)(src + jj * HID + k4);
            if (tid < TJ) pred = dbh[(t + 1) * TJ + tid];
        }

        unsigned long long wA = brA[t], wB = brB[t];

        float4 xj4[8];
#pragma unroll
        for (int q = 0; q < 8; ++q) xj4[q] = *(const float4*)&xs[bc][l][4 * q];
        float dj = xd[bc][l];

        // e = 0.6*(d_i+d_j) + sum_k 0.4*wa_k*|x_i+x_j|  (== wa . lrelu(x_i+x_j))
        float sA0 = 0.f, sA1 = 0.f, sA2 = 0.f, sA3 = 0.f;
        float sB0 = 0.f, sB1 = 0.f, sB2 = 0.f, sB3 = 0.f;
#pragma unroll
        for (int q = 0; q < 8; ++q) {
            float4 xv = xj4[q];
            float v;
            v = xiA[4*q+0] + xv.x; sA0 = fmaf(wa4[4*q+0], fabsf(v), sA0);
            v = xiA[4*q+1] + xv.y; sA1 = fmaf(wa4[4*q+1], fabsf(v), sA1);
            v = xiA[4*q+2] + xv.z; sA2 = fmaf(wa4[4*q+2], fabsf(v), sA2);
            v = xiA[4*q+3] + xv.w; sA3 = fmaf(wa4[4*q+3], fabsf(v), sA3);
            v = xiB[4*q+0] + xv.x; sB0 = fmaf(wa4[4*q+0], fabsf(v), sB0);
            v = xiB[4*q+1] + xv.y; sB1 = fmaf(wa4[4*q+1], fabsf(v), sB1);
            v = xiB[4*q+2] + xv.z; sB2 = fmaf(wa4[4*q+2], fabsf(v), sB2);
            v = xiB[4*q+3] + xv.w; sB3 = fmaf(wa4[4*q+3], fabsf(v), sB3);
        }
        float eA = (ciA + dj) + ((sA0 + sA1) + (sA2 + sA3));
        float eB = (ciB + dj) + ((sB0 + sB1) + (sB2 + sB3));
        float pA = ((wA >> l) & 1ull) ? __expf(eA) : 0.f;   // fixed m=0
        float pB = ((wB >> l) & 1ull) ? __expf(eB) : 0.f;
        lsA += pA;
        lsB += pB;
#pragma unroll
        for (int q = 0; q < 8; ++q) {
            float4 xv = xj4[q];
            accA[4*q+0] = fmaf(pA, xv.x, accA[4*q+0]);
            accA[4*q+1] = fmaf(pA, xv.y, accA[4*q+1]);
            accA[4*q+2] = fmaf(pA, xv.z, accA[4*q+2]);
            accA[4*q+3] = fmaf(pA, xv.w, accA[4*q+3]);
            accB[4*q+0] = fmaf(pB, xv.x, accB[4*q+0]);
            accB[4*q+1] = fmaf(pB, xv.y, accB[4*q+1]);
            accB[4*q+2] = fmaf(pB, xv.z, accB[4*q+2]);
            accB[4*q+3] = fmaf(pB, xv.w, accB[4*q+3]);
        }
    }

    // ---- epilogue: denominator butterfly, then cross-lane transpose-reduce via LDS
#pragma unroll
    for (int off = 32; off >= 1; off >>= 1) {
        lsA += __shfl_xor(lsA, off, 64);
        lsB += __shfl_xor(lsB, off, 64);
    }
    float invA = 1.0f / lsA, invB = 1.0f / lsB;
    int q = w & 3;
    float* orowA = out + ((size_t)(b * NN + iA)) * (HH * HID) + h * HID;
    float* orowB = out + ((size_t)(b * NN + iB)) * (HH * HID) + h * HID;

    __syncthreads();
    if (w < 4) {
#pragma unroll
        for (int k = 0; k < HID; ++k) scr[q][k][l] = accA[k];
        float sA = 0.f;
        if (l < HID) {
#pragma unroll
            for (int m = 0; m < 64; ++m) sA += scr[q][l][m];
        }
#pragma unroll
        for (int k = 0; k < HID; ++k) scr[q][k][l] = accB[k];
        float sB = 0.f;
        if (l < HID) {
#pragma unroll
            for (int m = 0; m < 64; ++m) sB += scr[q][l][m];
            orowA[l] = sA * invA;
            orowB[l] = sB * invB;
        }
    }
    __syncthreads();
    if (w >= 4) {
#pragma unroll
        for (int k = 0; k < HID; ++k) scr[q][k][l] = accA[k];
        float sA = 0.f;
        if (l < HID) {
#pragma unroll
            for (int m = 0; m < 64; ++m) sA += scr[q][l][m];
        }
#pragma unroll
        for (int k = 0; k < HID; ++k) scr[q][k][l] = accB[k];
        float sB = 0.f;
        if (l < HID) {
#pragma unroll
            for (int m = 0; m < 64; ++m) sB += scr[q][l][m];
            orowA[l] = sA * invA;
            orowB[l] = sB * invB;
        }
    }
}

extern "C" void kernel_launch(void* const* d_in, const int* in_sizes, int n_in,
                              void* d_out, int out_size, void* d_ws, size_t ws_size,
                              hipStream_t stream) {
    const float* node_feat = (const float*)d_in[0];
    const int*   adj_mtx   = (const int*)d_in[1];
    const float* W         = (const float*)d_in[2];
    const float* Wa        = (const float*)d_in[3];
    float* out = (float*)d_out;

    char* ws = (char*)d_ws;
    float*              x_ws  = (float*)(ws + WS_X);
    float*              d6_ws = (float*)(ws + WS_D6);
    unsigned long long* bits  = (unsigned long long*)(ws + WS_BITS);

    hipLaunchKernelGGL(gat_proj_kernel, dim3(BB * NN / 8), dim3(128), 0, stream,
                       node_feat, W, Wa, x_ws, d6_ws);
    hipLaunchKernelGGL(gat_pack_kernel, dim3(BB * NN * NN / 256), dim3(256), 0, stream,
                       adj_mtx, bits);
    hipLaunchKernelGGL(gat_attn_kernel, dim3(BB * HH * NN / 16), dim3(512), 0, stream,
                       x_ws, d6_ws, bits, Wa, out);
}